// Round 6
// baseline (196.614 us; speedup 1.0000x reference)
//
#include <hip/hip_runtime.h>
#include <math.h>

// Problem constants
#define B_   64
#define S_   64
#define W_   12
#define V_   32000
#define SYM_ 128
#define HID_ 256
#define E_   64
#define R_   32

typedef short bf16x8 __attribute__((ext_vector_type(8)));
typedef float f32x4 __attribute__((ext_vector_type(4)));
#define MFMA16 __builtin_amdgcn_mfma_f32_16x16x32_bf16

__device__ __forceinline__ float fast_tanh(float x) {
  float e = __expf(2.0f * x);
  return 1.0f - 2.0f * __builtin_amdgcn_rcpf(e + 1.0f);
}

__device__ __forceinline__ float bcastf(float v, int lane) {
  return __int_as_float(__builtin_amdgcn_readlane(__float_as_int(v), lane));
}

// fp32 -> bf16 hi (truncate) + bf16 lo (RNE of exact residual).
__device__ __forceinline__ void split1(float x, unsigned short& h, unsigned short& l) {
  unsigned u = __float_as_uint(x);
  h = (unsigned short)(u >> 16);
  float r = x - __uint_as_float(u & 0xFFFF0000u);
  unsigned v = __float_as_uint(r);
  l = (unsigned short)((v + 0x7FFFu + ((v >> 16) & 1u)) >> 16);
}

// ---------------------------------------------------------------------------
// K_prep: fused embed (blocks 0..4159) + wprep (blocks 4160..5119).
// Embed now writes X directly as bf16 hi/lo in MFMA FRAGMENT ORDER:
//   k-convention k = ks*32 + (lane>>4)*8 + j  (same as prepped weights)
//   addr = (tile16*4 + ks)*512 + lane*8 + j,  tile16 = row>>4, lane = lk*16+lr
// so k_mlp layer-1 A-frags are single coalesced b128 loads (no per-block
// re-split, no strided fp32 gathers).
// ---------------------------------------------------------------------------
__global__ __launch_bounds__(128) void k_prep(
    const int* __restrict__ story, const int* __restrict__ query,
    const float* __restrict__ we, const float* __restrict__ pe,
    unsigned short* __restrict__ Xh, unsigned short* __restrict__ Xl,
    const float* __restrict__ ueW1, const float* __restrict__ urW1,
    const float* __restrict__ ieW1, const float* __restrict__ irW1,
    const float* __restrict__ ueW2, const float* __restrict__ urW2,
    const float* __restrict__ ieW2, const float* __restrict__ irW2,
    unsigned short* __restrict__ w1ph, unsigned short* __restrict__ w1pl,
    unsigned short* __restrict__ w2ph, unsigned short* __restrict__ w2pl) {
  if (blockIdx.x < 4160) {
    // ---- embed ----
    int row = blockIdx.x;
    int e = threadIdx.x;
    const int* idx = (row < 4096) ? story + row * W_ : query + (row - 4096) * W_;
    float acc = 0.f;
#pragma unroll
    for (int w = 0; w < W_; ++w)
      acc = fmaf(we[(long)idx[w] * SYM_ + e], pe[w * SYM_ + e], acc);
    unsigned short hh, ll;
    split1(acc, hh, ll);
    int tile16 = row >> 4, lr = row & 15;
    int ks = e >> 5, lk = (e >> 3) & 3, j = e & 7;
    long addr = ((long)(tile16 * 4 + ks)) * 512 + (lk * 16 + lr) * 8 + j;
    Xh[addr] = hh;
    Xl[addr] = ll;
    return;
  }
  // ---- wprep ----
  int l = threadIdx.x;
  if (l >= 64) return;
  int bid = blockIdx.x - 4160;
  bf16x8 h8, l8;
  if (bid < 640) {                      // W1 frags: 10 slots x 16 nt x 4 ks
    int slot = bid >> 6, rem = bid & 63;
    int nt = rem >> 2, ks = rem & 3;
    int grp = slot / 5, h = slot % 5;
    const float* src = (h < 2) ? ((grp ? ieW1 : ueW1) + h * (SYM_ * HID_))
                               : ((grp ? irW1 : urW1) + (h - 2) * (SYM_ * HID_));
    int kk = ks * 32 + (l >> 4) * 8;
    int n = nt * 16 + (l & 15);
#pragma unroll
    for (int j = 0; j < 8; ++j) {
      unsigned short hh, ll;
      split1(src[(long)(kk + j) * HID_ + n], hh, ll);
      h8[j] = (short)hh;
      l8[j] = (short)ll;
    }
    long dst = ((long)(slot * 16 + nt) * 4 + ks) * 512 + l * 8;
    *(bf16x8*)(w1ph + dst) = h8;
    *(bf16x8*)(w1pl + dst) = l8;
  } else {                              // W2 frags: 10 slots x 4 nt x 8 ks
    int fid = bid - 640;
    int slot = fid >> 5, rem = fid & 31;
    int nt = rem >> 3, ks = rem & 7;
    int grp = slot / 5, h = slot % 5;
    bool isE = h < 2;
    if (!isE && nt >= 2) return;        // R heads: only 32 out cols
    int NC = isE ? E_ : R_;
    const float* src = isE ? ((grp ? ieW2 : ueW2) + h * (HID_ * E_))
                           : ((grp ? irW2 : urW2) + (h - 2) * (HID_ * R_));
    int kk = ks * 32 + (l >> 4) * 8;
    int n = nt * 16 + (l & 15);
#pragma unroll
    for (int j = 0; j < 8; ++j) {
      unsigned short hh, ll;
      split1(src[(long)(kk + j) * NC + n], hh, ll);
      h8[j] = (short)hh;
      l8[j] = (short)ll;
    }
    long dst = ((long)(slot * 4 + nt) * 8 + ks) * 512 + l * 8;
    *(bf16x8*)(w2ph + dst) = h8;
    *(bf16x8*)(w2pl + dst) = l8;
  }
}

// ---------------------------------------------------------------------------
// K2 v12: MFMA MLP, A-frags pre-split & frag-ordered (pure b128 loads).
// Block = 256 thr (4 waves), 32-row tile, 1 head; grid 650.
// ---------------------------------------------------------------------------
__global__ __launch_bounds__(256) void k_mlp(
    const unsigned short* __restrict__ Xh, const unsigned short* __restrict__ Xl,
    const unsigned short* __restrict__ w1ph, const unsigned short* __restrict__ w1pl,
    const unsigned short* __restrict__ w2ph, const unsigned short* __restrict__ w2pl,
    const float* __restrict__ ueb1, const float* __restrict__ urb1,
    const float* __restrict__ ieb1, const float* __restrict__ irb1,
    const float* __restrict__ ueb2, const float* __restrict__ urb2,
    const float* __restrict__ ieb2, const float* __restrict__ irb2,
    float* __restrict__ oE0, float* __restrict__ oE1,
    float* __restrict__ oR0, float* __restrict__ oR1, float* __restrict__ oR2) {
  __shared__ unsigned short Hhi[32][264];
  __shared__ unsigned short Hlo[32][264];

  int h = blockIdx.x % 5;
  int tile = blockIdx.x / 5;
  int rowbase = tile * 32;
  int grp = (rowbase >= 4096) ? 1 : 0;
  bool isE = (h < 2);
  int slot = grp * 5 + h;
  const float* b1 = isE ? ((grp ? ieb1 : ueb1) + h * HID_)
                        : ((grp ? irb1 : urb1) + (h - 2) * HID_);
  const float* b2 = isE ? ((grp ? ieb2 : ueb2) + h * E_)
                        : ((grp ? irb2 : urb2) + (h - 2) * R_);
  float* out = (h == 0) ? oE0 : (h == 1) ? oE1 : (h == 2) ? oR0 : (h == 3) ? oR1 : oR2;

  int tid = threadIdx.x;
  int w = tid >> 6;
  int l = tid & 63;
  int lr = l & 15;
  int lk = l >> 4;

  // ---- layer 1 ----
  f32x4 acc[2][4];
#pragma unroll
  for (int mt = 0; mt < 2; ++mt)
#pragma unroll
    for (int ntl = 0; ntl < 4; ++ntl) acc[mt][ntl] = (f32x4){0.f, 0.f, 0.f, 0.f};

  const unsigned short* w1hS = w1ph + (long)slot * 32768 + l * 8;
  const unsigned short* w1lS = w1pl + (long)slot * 32768 + l * 8;
  int tile2 = tile * 2;

#pragma unroll
  for (int ks = 0; ks < 4; ++ks) {
    bf16x8 ah[2], al[2];
#pragma unroll
    for (int mt = 0; mt < 2; ++mt) {
      long base = ((long)((tile2 + mt) * 4 + ks)) * 512 + l * 8;
      ah[mt] = *(const bf16x8*)(Xh + base);
      al[mt] = *(const bf16x8*)(Xl + base);
    }
#pragma unroll
    for (int ntl = 0; ntl < 4; ++ntl) {
      int nt = 4 * w + ntl;
      long fo = ((long)nt * 4 + ks) * 512;
      bf16x8 bh = *(const bf16x8*)(w1hS + fo);
      bf16x8 bl = *(const bf16x8*)(w1lS + fo);
#pragma unroll
      for (int mt = 0; mt < 2; ++mt) {
        acc[mt][ntl] = MFMA16(ah[mt], bh, acc[mt][ntl], 0, 0, 0);
        acc[mt][ntl] = MFMA16(ah[mt], bl, acc[mt][ntl], 0, 0, 0);
        acc[mt][ntl] = MFMA16(al[mt], bh, acc[mt][ntl], 0, 0, 0);
      }
    }
  }

  // bias + tanh -> split -> H LDS
#pragma unroll
  for (int ntl = 0; ntl < 4; ++ntl) {
    int col = (4 * w + ntl) * 16 + lr;
    float bb = b1[col];
#pragma unroll
    for (int mt = 0; mt < 2; ++mt)
#pragma unroll
      for (int reg = 0; reg < 4; ++reg) {
        float t = fast_tanh(acc[mt][ntl][reg] + bb);
        unsigned short hh, ll;
        split1(t, hh, ll);
        int row = mt * 16 + lk * 4 + reg;
        Hhi[row][col] = hh;
        Hlo[row][col] = ll;
      }
  }
  __syncthreads();

  // ---- layer 2 ----
  if (isE) {
    const unsigned short* w2hS = w2ph + (long)slot * 16384 + l * 8;
    const unsigned short* w2lS = w2pl + (long)slot * 16384 + l * 8;
    int nt2 = w;
    f32x4 acc2[2];
    acc2[0] = (f32x4){0.f, 0.f, 0.f, 0.f};
    acc2[1] = (f32x4){0.f, 0.f, 0.f, 0.f};
#pragma unroll
    for (int ks2 = 0; ks2 < 8; ++ks2) {
      long fo = ((long)nt2 * 8 + ks2) * 512;
      bf16x8 bh = *(const bf16x8*)(w2hS + fo);
      bf16x8 bl = *(const bf16x8*)(w2lS + fo);
#pragma unroll
      for (int mt = 0; mt < 2; ++mt) {
        int row = mt * 16 + lr, kh = ks2 * 32 + lk * 8;
        bf16x8 ah2 = *(const bf16x8*)&Hhi[row][kh];
        bf16x8 al2 = *(const bf16x8*)&Hlo[row][kh];
        acc2[mt] = MFMA16(ah2, bh, acc2[mt], 0, 0, 0);
        acc2[mt] = MFMA16(ah2, bl, acc2[mt], 0, 0, 0);
        acc2[mt] = MFMA16(al2, bh, acc2[mt], 0, 0, 0);
      }
    }
    int col2 = nt2 * 16 + lr;
    float bb2 = b2[col2];
#pragma unroll
    for (int mt = 0; mt < 2; ++mt)
#pragma unroll
      for (int reg = 0; reg < 4; ++reg)
        out[(long)(rowbase + mt * 16 + lk * 4 + reg) * E_ + col2] = acc2[mt][reg] + bb2;
  } else {
    const unsigned short* w2hS = w2ph + (long)slot * 16384 + l * 8;
    const unsigned short* w2lS = w2pl + (long)slot * 16384 + l * 8;
    int mt = w >> 1, nt2 = w & 1;
    f32x4 acc2 = (f32x4){0.f, 0.f, 0.f, 0.f};
#pragma unroll
    for (int ks2 = 0; ks2 < 8; ++ks2) {
      long fo = ((long)nt2 * 8 + ks2) * 512;
      bf16x8 bh = *(const bf16x8*)(w2hS + fo);
      bf16x8 bl = *(const bf16x8*)(w2lS + fo);
      int row = mt * 16 + lr, kh = ks2 * 32 + lk * 8;
      bf16x8 ah2 = *(const bf16x8*)&Hhi[row][kh];
      bf16x8 al2 = *(const bf16x8*)&Hlo[row][kh];
      acc2 = MFMA16(ah2, bh, acc2, 0, 0, 0);
      acc2 = MFMA16(ah2, bl, acc2, 0, 0, 0);
      acc2 = MFMA16(al2, bh, acc2, 0, 0, 0);
    }
    int col2 = nt2 * 16 + lr;
    float bb2 = b2[col2];
#pragma unroll
    for (int reg = 0; reg < 4; ++reg)
      out[(long)(rowbase + mt * 16 + lk * 4 + reg) * R_ + col2] = acc2[reg] + bb2;
  }
}

// ---------------------------------------------------------------------------
// K_gram v2 (unchanged)
// ---------------------------------------------------------------------------
__global__ __launch_bounds__(256) void k_gram(
    const float* __restrict__ e1, const float* __restrict__ e2,
    const float* __restrict__ r1, const float* __restrict__ r2,
    const float* __restrict__ r3, float* __restrict__ Wt) {
  int b = blockIdx.x / 9, m = blockIdx.x % 9;
  const float* sE = ((m < 6) ? e1 : e2) + (long)b * S_ * E_;
  const float* jE = ((m == 2 || m == 5 || m == 8) ? e2 : e1) + (long)b * S_ * E_;
  int sk = m / 3, jk = m % 3;
  const float* sR = ((sk == 0) ? r1 : (sk == 1) ? r2 : r3) + (long)b * S_ * R_;
  const float* jR = ((jk == 0) ? r1 : (jk == 1) ? r2 : r3) + (long)b * S_ * R_;

  __shared__ float Es[64][68], Ej[64][68], Rs[64][36], Rj[64][36];
  int tid = threadIdx.x;
  for (int i = tid; i < 1024; i += 256) {
    int row = i >> 4, c = i & 15;
    *(float4*)&Es[row][4 * c] = *(const float4*)(sE + row * 64 + 4 * c);
    *(float4*)&Ej[row][4 * c] = *(const float4*)(jE + row * 64 + 4 * c);
  }
  for (int i = tid; i < 512; i += 256) {
    int row = i >> 3, c = i & 7;
    *(float4*)&Rs[row][4 * c] = *(const float4*)(sR + row * 32 + 4 * c);
    *(float4*)&Rj[row][4 * c] = *(const float4*)(jR + row * 32 + 4 * c);
  }
  __syncthreads();

  int s0 = (tid & 15) * 4, j0 = (tid >> 4) * 4;
  float ed[4][4] = {}, rd[4][4] = {};
#pragma unroll 4
  for (int k = 0; k < 16; ++k) {
    float4 es[4], ej[4];
#pragma unroll
    for (int i = 0; i < 4; ++i) {
      es[i] = *(const float4*)&Es[s0 + i][4 * k];
      ej[i] = *(const float4*)&Ej[j0 + i][4 * k];
    }
#pragma unroll
    for (int i = 0; i < 4; ++i)
#pragma unroll
      for (int j = 0; j < 4; ++j)
        ed[i][j] = fmaf(es[i].x, ej[j].x, fmaf(es[i].y, ej[j].y,
                   fmaf(es[i].z, ej[j].z, fmaf(es[i].w, ej[j].w, ed[i][j]))));
  }
#pragma unroll 4
  for (int k = 0; k < 8; ++k) {
    float4 rs[4], rj[4];
#pragma unroll
    for (int i = 0; i < 4; ++i) {
      rs[i] = *(const float4*)&Rs[s0 + i][4 * k];
      rj[i] = *(const float4*)&Rj[j0 + i][4 * k];
    }
#pragma unroll
    for (int i = 0; i < 4; ++i)
#pragma unroll
      for (int j = 0; j < 4; ++j)
        rd[i][j] = fmaf(rs[i].x, rj[j].x, fmaf(rs[i].y, rj[j].y,
                   fmaf(rs[i].z, rj[j].z, fmaf(rs[i].w, rj[j].w, rd[i][j]))));
  }
  float* wout = Wt + (long)(b * 9 + m) * 4096;
#pragma unroll
  for (int jj = 0; jj < 4; ++jj) {
    float4 o4 = make_float4(ed[0][jj] * rd[0][jj], ed[1][jj] * rd[1][jj],
                            ed[2][jj] * rd[2][jj], ed[3][jj] * rd[3][jj]);
    *(float4*)(wout + (j0 + jj) * 64 + s0) = o4;
  }
}

// ---------------------------------------------------------------------------
// K_scan v7 (unchanged from R5)
// ---------------------------------------------------------------------------
__global__ __launch_bounds__(256) void k_scan(
    const float* __restrict__ e1g, const float* __restrict__ e2g,
    const float* __restrict__ Wt, float4* __restrict__ acd) {
  __shared__ float WtL[8][64][12];
  int b = blockIdx.x & 63;
  int gq = blockIdx.x >> 6;        // 0..3
  int tid = threadIdx.x;
  int wv = tid >> 6;
  int lane = tid & 63;             // = s
  int fbase = gq * 16 + wv * 4;    // lane handles f = fbase..fbase+3
  const float* Wb = Wt + (long)b * 9 * 4096;
  long eoff = ((long)b * 64 + lane) * 64;
  float4 e1v = *(const float4*)(e1g + eoff + fbase);
  float4 e2v = *(const float4*)(e2g + eoff + fbase);
  float e1a[4] = {e1v.x, e1v.y, e1v.z, e1v.w};
  float e2a[4] = {e2v.x, e2v.y, e2v.z, e2v.w};

  float pW[4], pM[4], pB[4], ca[4], cc[4], cd[4], ka[4], kc[4], kd[4];
#pragma unroll
  for (int f = 0; f < 4; ++f) {
    pW[f] = pM[f] = pB[f] = 0.f;
    ka[f] = kc[f] = kd[f] = 0.f;
    ca[f] = e2a[f]; cc[f] = 0.f; cd[f] = e1a[f];
  }

  for (int jc = 0; jc < 8; ++jc) {
    __syncthreads();
#pragma unroll
    for (int t = 0; t < 2; ++t) {
      int jj = wv * 2 + t;
      const float* src = Wb + jc * 512 + jj * 64 + lane;
      float v[9];
#pragma unroll
      for (int m = 0; m < 9; ++m) v[m] = src[m * 4096];
      float* dst = &WtL[jj][lane][0];
      *(float4*)dst = make_float4(v[0], v[1], v[2], v[3]);
      *(float4*)(dst + 4) = make_float4(v[4], v[5], v[6], v[7]);
      dst[8] = v[8];
    }
    __syncthreads();
#pragma unroll
    for (int jj = 0; jj < 8; ++jj) {
      int j = jc * 8 + jj;
      const float* wrow = &WtL[jj][lane][0];
      float4 w03 = *(const float4*)wrow;
      float4 w47 = *(const float4*)(wrow + 4);
      float bd = wrow[8];
      float wa = w03.x, wc = w03.y, wd = w03.z;
      float ma = w03.w, mc = w47.x, md = w47.y;
      float ba = w47.z, bc = w47.w;
      bool own = (lane == j);
#pragma unroll
      for (int f = 0; f < 4; ++f) {
        float aj = bcastf(ca[f], j);
        float cj = bcastf(cc[f], j);
        float dj = bcastf(cd[f], j);
        ka[f] = own ? ca[f] : ka[f];
        kc[f] = own ? cc[f] : kc[f];
        kd[f] = own ? cd[f] : kd[f];
        pW[f] = fmaf(wa, aj, pW[f]); pW[f] = fmaf(wc, cj, pW[f]); pW[f] = fmaf(wd, dj, pW[f]);
        pM[f] = fmaf(ma, aj, pM[f]); pM[f] = fmaf(mc, cj, pM[f]); pM[f] = fmaf(md, dj, pM[f]);
        pB[f] = fmaf(ba, aj, pB[f]); pB[f] = fmaf(bc, cj, pB[f]); pB[f] = fmaf(bd, dj, pB[f]);
        ca[f] = e2a[f] - pW[f]; cc[f] = pW[f] - pM[f]; cd[f] = e1a[f] - pB[f];
      }
    }
  }
#pragma unroll
  for (int f = 0; f < 4; ++f)
    acd[eoff + fbase + f] = make_float4(ka[f], kc[f], kd[f], 0.f);
}

// ---------------------------------------------------------------------------
// K_infer v2: 256 threads (4-wave barriers instead of 16-wave).
// u-dots: 2 thr/dot (32 elems + shfl_xor(1)); part: 4 thr/f (16 j + 2 shfl).
// ---------------------------------------------------------------------------
__global__ __launch_bounds__(256) void k_infer(
    const float4* __restrict__ acd,
    const float* __restrict__ e1, const float* __restrict__ e2,
    const float* __restrict__ r1, const float* __restrict__ r2,
    const float* __restrict__ r3,
    const float* __restrict__ qe1, const float* __restrict__ qr1,
    const float* __restrict__ qr2, const float* __restrict__ qr3,
    const float* __restrict__ lng, const float* __restrict__ lnb,
    float* __restrict__ isum) {
  int b = blockIdx.x, tid = threadIdx.x;
  __shared__ float hista[64 * 65], histc[64 * 65], histd[64 * 65];
  __shared__ float vlds[9 * 64];
  __shared__ float ivec[64];
  __shared__ float u1s[64], u2s[64];
  __shared__ float dsc[64];

  {
    const float4* ab = acd + (long)b * 4096;
    for (int idx = tid; idx < 4096; idx += 256) {
      float4 hv = ab[idx];
      int j = idx >> 6, f = idx & 63;
      hista[j * 65 + f] = hv.x;
      histc[j * 65 + f] = hv.y;
      histd[j * 65 + f] = hv.z;
    }
  }
  for (int i = tid; i < 576; i += 256) {
    int pk = i >> 6, j = i & 63;
    int p = pk / 3, k = pk % 3;
    const float* rv = ((k == 0) ? r1 : (k == 1) ? r2 : r3) + ((long)b * 64 + j) * 32;
    const float* q = ((p == 0) ? qr1 : (p == 1) ? qr2 : qr3) + b * 32;
    float acc = 0.f;
#pragma unroll
    for (int t = 0; t < 8; ++t) {
      float4 rv4 = *(const float4*)(rv + 4 * t);
      float4 q4 = *(const float4*)(q + 4 * t);
      acc = fmaf(rv4.x, q4.x, fmaf(rv4.y, q4.y,
            fmaf(rv4.z, q4.z, fmaf(rv4.w, q4.w, acc))));
    }
    vlds[pk * 64 + j] = acc;
  }
  if (tid < 64) ivec[tid] = qe1[b * 64 + tid];
  __syncthreads();

  int dotd = tid >> 1, dt = tid & 1;          // u-dot: 2 thr per dot
  int which = dotd >> 6, dj = dotd & 63;
  const float* erow = (which ? e2 : e1) + ((long)b * 64 + dj) * 64 + dt * 32;
  int f = tid >> 2, jq = tid & 3;             // part: 4 thr per f
  float isacc = 0.f;
  for (int p = 0; p < 3; ++p) {
    {
      float acc = 0.f;
#pragma unroll
      for (int t = 0; t < 8; ++t) {
        float4 ev = *(const float4*)(erow + 4 * t);
        int kb = dt * 32 + 4 * t;
        acc = fmaf(ev.x, ivec[kb], fmaf(ev.y, ivec[kb + 1],
              fmaf(ev.z, ivec[kb + 2], fmaf(ev.w, ivec[kb + 3], acc))));
      }
      acc += __shfl_xor(acc, 1, 64);
      if (dt == 0) { if (which) u2s[dj] = acc; else u1s[dj] = acc; }
    }
    __syncthreads();
    float part = 0.f;
#pragma unroll
    for (int i = 0; i < 16; ++i) {
      int j = jq * 16 + i;
      float ca = u1s[j] * vlds[(p * 3 + 0) * 64 + j];
      float cc = u1s[j] * vlds[(p * 3 + 1) * 64 + j];
      float cd = u2s[j] * vlds[(p * 3 + 2) * 64 + j];
      part = fmaf(ca, hista[j * 65 + f],
             fmaf(cc, histc[j * 65 + f],
             fmaf(cd, histd[j * 65 + f], part)));
    }
    part += __shfl_xor(part, 1, 64);
    part += __shfl_xor(part, 2, 64);
    if (jq == 0) dsc[f] = part;
    __syncthreads();
    if (tid < 64) {
      float v = dsc[tid];
      float mu = v;
#pragma unroll
      for (int mm = 1; mm <= 32; mm <<= 1) mu += __shfl_xor(mu, mm, 64);
      mu *= (1.f / 64.f);
      float d = v - mu;
      float vr = d * d;
#pragma unroll
      for (int mm = 1; mm <= 32; mm <<= 1) vr += __shfl_xor(vr, mm, 64);
      vr *= (1.f / 64.f);
      float iv = d * (1.f / sqrtf(vr + 1e-5f)) * lng[p * 64 + tid] + lnb[p * 64 + tid];
      ivec[tid] = iv;
      isacc += iv;
    }
    __syncthreads();
  }
  if (tid < 64) isum[b * 64 + tid] = isacc;
}

// ---------------------------------------------------------------------------
// K5 (unchanged)
// ---------------------------------------------------------------------------
__global__ __launch_bounds__(256) void k_final(
    const float* __restrict__ isum, const float* __restrict__ Zm,
    float* __restrict__ out) {
  __shared__ float isT[64 * 68];
  int tid = threadIdx.x;
  for (int i = tid; i < 4096; i += 256) {
    int bb = i >> 6, e = i & 63;
    isT[e * 68 + bb] = isum[i];
  }
  __syncthreads();
  int tr = tid >> 4, tc = tid & 15;
  int v0 = blockIdx.x * 64 + tc * 4;
  float acc[4][4] = {};
#pragma unroll 2
  for (int e = 0; e < 64; ++e) {
    float4 a4 = *(const float4*)&isT[e * 68 + 4 * tr];
    float4 z4 = *(const float4*)(Zm + (long)e * V_ + v0);
    float as[4] = {a4.x, a4.y, a4.z, a4.w};
    float zs[4] = {z4.x, z4.y, z4.z, z4.w};
#pragma unroll
    for (int i = 0; i < 4; ++i)
#pragma unroll
      for (int j = 0; j < 4; ++j) acc[i][j] = fmaf(as[i], zs[j], acc[i][j]);
  }
#pragma unroll
  for (int i = 0; i < 4; ++i) {
    float4 o4 = make_float4(acc[i][0], acc[i][1], acc[i][2], acc[i][3]);
    *(float4*)(out + (long)(4 * tr + i) * V_ + v0) = o4;
  }
}

// ---------------------------------------------------------------------------
extern "C" void kernel_launch(void* const* d_in, const int* in_sizes, int n_in,
                              void* d_out, int out_size, void* d_ws, size_t ws_size,
                              hipStream_t stream) {
  const int* story = (const int*)d_in[0];
  const int* query = (const int*)d_in[1];
  const float* we = (const float*)d_in[2];
  const float* pe = (const float*)d_in[3];
  const float* ueW1 = (const float*)d_in[4];
  const float* ueb1 = (const float*)d_in[5];
  const float* ueW2 = (const float*)d_in[6];
  const float* ueb2 = (const float*)d_in[7];
  const float* urW1 = (const float*)d_in[8];
  const float* urb1 = (const float*)d_in[9];
  const float* urW2 = (const float*)d_in[10];
  const float* urb2 = (const float*)d_in[11];
  const float* ieW1 = (const float*)d_in[12];
  const float* ieb1 = (const float*)d_in[13];
  const float* ieW2 = (const float*)d_in[14];
  const float* ieb2 = (const float*)d_in[15];
  const float* irW1 = (const float*)d_in[16];
  const float* irb1 = (const float*)d_in[17];
  const float* irW2 = (const float*)d_in[18];
  const float* irb2 = (const float*)d_in[19];
  const float* lng = (const float*)d_in[20];
  const float* lnb = (const float*)d_in[21];
  const float* Zm = (const float*)d_in[22];

  float* ws = (float*)d_ws;
  // X region now holds bf16 hi/lo in fragment order (4160*128 u16 each)
  unsigned short* Xh = (unsigned short*)ws;
  unsigned short* Xl = Xh + 532480;     // 1.06 MB each; together = old X slot
  float* e1 = ws + 532480;              // 4160*64  = 266240
  float* e2 = e1 + 266240;              // 266240
  float* r1 = e2 + 266240;              // 4160*32  = 133120
  float* r2 = r1 + 133120;              // 133120
  float* r3 = r2 + 133120;              // 133120
  float* isum = r3 + 133120;            // 4096
  float* Wt = isum + 4096;              // 9*64*4096 = 2359296
  float4* acd = (float4*)(Wt + 2359296);  // 64*64*64 float4 = 4 MB
  float* qe1 = e1 + 4096 * 64;
  float* qr1 = r1 + 4096 * 32;
  float* qr2 = r2 + 4096 * 32;
  float* qr3 = r3 + 4096 * 32;
  float* outF = (float*)d_out;

  // Prepped weights alias the Wt region (dead until k_gram runs).
  unsigned short* w1ph = (unsigned short*)Wt;
  unsigned short* w1pl = w1ph + 327680;   // 10*32768
  unsigned short* w2ph = w1pl + 327680;
  unsigned short* w2pl = w2ph + 163840;   // 10*16384

  k_prep<<<4160 + 960, 128, 0, stream>>>(story, query, we, pe, Xh, Xl,
                                         ueW1, urW1, ieW1, irW1,
                                         ueW2, urW2, ieW2, irW2,
                                         w1ph, w1pl, w2ph, w2pl);
  k_mlp<<<130 * 5, 256, 0, stream>>>(Xh, Xl, w1ph, w1pl, w2ph, w2pl,
                                     ueb1, urb1, ieb1, irb1,
                                     ueb2, urb2, ieb2, irb2,
                                     e1, e2, r1, r2, r3);
  k_gram<<<64 * 9, 256, 0, stream>>>(e1, e2, r1, r2, r3, Wt);
  k_scan<<<256, 256, 0, stream>>>(e1, e2, Wt, acd);
  k_infer<<<B_, 256, 0, stream>>>(acd, e1, e2, r1, r2, r3, qe1, qr1, qr2, qr3,
                                  lng, lnb, isum);
  k_final<<<V_ / 64, 256, 0, stream>>>(isum, Zm, outF);
}

// Round 7
// 194.554 us; speedup vs baseline: 1.0106x; 1.0106x over previous
//
#include <hip/hip_runtime.h>
#include <math.h>

// Problem constants
#define B_   64
#define S_   64
#define W_   12
#define V_   32000
#define SYM_ 128
#define HID_ 256
#define E_   64
#define R_   32

typedef short bf16x8 __attribute__((ext_vector_type(8)));
typedef float f32x4 __attribute__((ext_vector_type(4)));
#define MFMA16 __builtin_amdgcn_mfma_f32_16x16x32_bf16

__device__ __forceinline__ float fast_tanh(float x) {
  float e = __expf(2.0f * x);
  return 1.0f - 2.0f * __builtin_amdgcn_rcpf(e + 1.0f);
}

__device__ __forceinline__ float bcastf(float v, int lane) {
  return __int_as_float(__builtin_amdgcn_readlane(__float_as_int(v), lane));
}

// fp32 -> bf16 hi (truncate) + bf16 lo (RNE of exact residual).
__device__ __forceinline__ void split1(float x, unsigned short& h, unsigned short& l) {
  unsigned u = __float_as_uint(x);
  h = (unsigned short)(u >> 16);
  float r = x - __uint_as_float(u & 0xFFFF0000u);
  unsigned v = __float_as_uint(r);
  l = (unsigned short)((v + 0x7FFFu + ((v >> 16) & 1u)) >> 16);
}

// ---------------------------------------------------------------------------
// K_prep: fused embed (blocks 0..4159) + wprep (blocks 4160..5119).
// Embed writes X directly as bf16 hi/lo in MFMA FRAGMENT ORDER:
//   k-convention k = ks*32 + (lane>>4)*8 + j  (same as prepped weights)
//   addr = (tile16*4 + ks)*512 + lane*8 + j,  tile16 = row>>4, lane = lk*16+lr
// ---------------------------------------------------------------------------
__global__ __launch_bounds__(128) void k_prep(
    const int* __restrict__ story, const int* __restrict__ query,
    const float* __restrict__ we, const float* __restrict__ pe,
    unsigned short* __restrict__ Xh, unsigned short* __restrict__ Xl,
    const float* __restrict__ ueW1, const float* __restrict__ urW1,
    const float* __restrict__ ieW1, const float* __restrict__ irW1,
    const float* __restrict__ ueW2, const float* __restrict__ urW2,
    const float* __restrict__ ieW2, const float* __restrict__ irW2,
    unsigned short* __restrict__ w1ph, unsigned short* __restrict__ w1pl,
    unsigned short* __restrict__ w2ph, unsigned short* __restrict__ w2pl) {
  if (blockIdx.x < 4160) {
    // ---- embed ----
    int row = blockIdx.x;
    int e = threadIdx.x;
    const int* idx = (row < 4096) ? story + row * W_ : query + (row - 4096) * W_;
    float acc = 0.f;
#pragma unroll
    for (int w = 0; w < W_; ++w)
      acc = fmaf(we[(long)idx[w] * SYM_ + e], pe[w * SYM_ + e], acc);
    unsigned short hh, ll;
    split1(acc, hh, ll);
    int tile16 = row >> 4, lr = row & 15;
    int ks = e >> 5, lk = (e >> 3) & 3, j = e & 7;
    long addr = ((long)(tile16 * 4 + ks)) * 512 + (lk * 16 + lr) * 8 + j;
    Xh[addr] = hh;
    Xl[addr] = ll;
    return;
  }
  // ---- wprep ----
  int l = threadIdx.x;
  if (l >= 64) return;
  int bid = blockIdx.x - 4160;
  bf16x8 h8, l8;
  if (bid < 640) {                      // W1 frags: 10 slots x 16 nt x 4 ks
    int slot = bid >> 6, rem = bid & 63;
    int nt = rem >> 2, ks = rem & 3;
    int grp = slot / 5, h = slot % 5;
    const float* src = (h < 2) ? ((grp ? ieW1 : ueW1) + h * (SYM_ * HID_))
                               : ((grp ? irW1 : urW1) + (h - 2) * (SYM_ * HID_));
    int kk = ks * 32 + (l >> 4) * 8;
    int n = nt * 16 + (l & 15);
#pragma unroll
    for (int j = 0; j < 8; ++j) {
      unsigned short hh, ll;
      split1(src[(long)(kk + j) * HID_ + n], hh, ll);
      h8[j] = (short)hh;
      l8[j] = (short)ll;
    }
    long dst = ((long)(slot * 16 + nt) * 4 + ks) * 512 + l * 8;
    *(bf16x8*)(w1ph + dst) = h8;
    *(bf16x8*)(w1pl + dst) = l8;
  } else {                              // W2 frags: 10 slots x 4 nt x 8 ks
    int fid = bid - 640;
    int slot = fid >> 5, rem = fid & 31;
    int nt = rem >> 3, ks = rem & 7;
    int grp = slot / 5, h = slot % 5;
    bool isE = h < 2;
    if (!isE && nt >= 2) return;        // R heads: only 32 out cols
    int NC = isE ? E_ : R_;
    const float* src = isE ? ((grp ? ieW2 : ueW2) + h * (HID_ * E_))
                           : ((grp ? irW2 : urW2) + (h - 2) * (HID_ * R_));
    int kk = ks * 32 + (l >> 4) * 8;
    int n = nt * 16 + (l & 15);
#pragma unroll
    for (int j = 0; j < 8; ++j) {
      unsigned short hh, ll;
      split1(src[(long)(kk + j) * NC + n], hh, ll);
      h8[j] = (short)hh;
      l8[j] = (short)ll;
    }
    long dst = ((long)(slot * 4 + nt) * 8 + ks) * 512 + l * 8;
    *(bf16x8*)(w2ph + dst) = h8;
    *(bf16x8*)(w2pl + dst) = l8;
  }
}

// ---------------------------------------------------------------------------
// K2 v12: MFMA MLP, A-frags pre-split & frag-ordered (pure b128 loads).
// Block = 256 thr (4 waves), 32-row tile, 1 head; grid 650.
// ---------------------------------------------------------------------------
__global__ __launch_bounds__(256) void k_mlp(
    const unsigned short* __restrict__ Xh, const unsigned short* __restrict__ Xl,
    const unsigned short* __restrict__ w1ph, const unsigned short* __restrict__ w1pl,
    const unsigned short* __restrict__ w2ph, const unsigned short* __restrict__ w2pl,
    const float* __restrict__ ueb1, const float* __restrict__ urb1,
    const float* __restrict__ ieb1, const float* __restrict__ irb1,
    const float* __restrict__ ueb2, const float* __restrict__ urb2,
    const float* __restrict__ ieb2, const float* __restrict__ irb2,
    float* __restrict__ oE0, float* __restrict__ oE1,
    float* __restrict__ oR0, float* __restrict__ oR1, float* __restrict__ oR2) {
  __shared__ unsigned short Hhi[32][264];
  __shared__ unsigned short Hlo[32][264];

  int h = blockIdx.x % 5;
  int tile = blockIdx.x / 5;
  int rowbase = tile * 32;
  int grp = (rowbase >= 4096) ? 1 : 0;
  bool isE = (h < 2);
  int slot = grp * 5 + h;
  const float* b1 = isE ? ((grp ? ieb1 : ueb1) + h * HID_)
                        : ((grp ? irb1 : urb1) + (h - 2) * HID_);
  const float* b2 = isE ? ((grp ? ieb2 : ueb2) + h * E_)
                        : ((grp ? irb2 : urb2) + (h - 2) * R_);
  float* out = (h == 0) ? oE0 : (h == 1) ? oE1 : (h == 2) ? oR0 : (h == 3) ? oR1 : oR2;

  int tid = threadIdx.x;
  int w = tid >> 6;
  int l = tid & 63;
  int lr = l & 15;
  int lk = l >> 4;

  // ---- layer 1 ----
  f32x4 acc[2][4];
#pragma unroll
  for (int mt = 0; mt < 2; ++mt)
#pragma unroll
    for (int ntl = 0; ntl < 4; ++ntl) acc[mt][ntl] = (f32x4){0.f, 0.f, 0.f, 0.f};

  const unsigned short* w1hS = w1ph + (long)slot * 32768 + l * 8;
  const unsigned short* w1lS = w1pl + (long)slot * 32768 + l * 8;
  int tile2 = tile * 2;

#pragma unroll
  for (int ks = 0; ks < 4; ++ks) {
    bf16x8 ah[2], al[2];
#pragma unroll
    for (int mt = 0; mt < 2; ++mt) {
      long base = ((long)((tile2 + mt) * 4 + ks)) * 512 + l * 8;
      ah[mt] = *(const bf16x8*)(Xh + base);
      al[mt] = *(const bf16x8*)(Xl + base);
    }
#pragma unroll
    for (int ntl = 0; ntl < 4; ++ntl) {
      int nt = 4 * w + ntl;
      long fo = ((long)nt * 4 + ks) * 512;
      bf16x8 bh = *(const bf16x8*)(w1hS + fo);
      bf16x8 bl = *(const bf16x8*)(w1lS + fo);
#pragma unroll
      for (int mt = 0; mt < 2; ++mt) {
        acc[mt][ntl] = MFMA16(ah[mt], bh, acc[mt][ntl], 0, 0, 0);
        acc[mt][ntl] = MFMA16(ah[mt], bl, acc[mt][ntl], 0, 0, 0);
        acc[mt][ntl] = MFMA16(al[mt], bh, acc[mt][ntl], 0, 0, 0);
      }
    }
  }

  // bias + tanh -> split -> H LDS
#pragma unroll
  for (int ntl = 0; ntl < 4; ++ntl) {
    int col = (4 * w + ntl) * 16 + lr;
    float bb = b1[col];
#pragma unroll
    for (int mt = 0; mt < 2; ++mt)
#pragma unroll
      for (int reg = 0; reg < 4; ++reg) {
        float t = fast_tanh(acc[mt][ntl][reg] + bb);
        unsigned short hh, ll;
        split1(t, hh, ll);
        int row = mt * 16 + lk * 4 + reg;
        Hhi[row][col] = hh;
        Hlo[row][col] = ll;
      }
  }
  __syncthreads();

  // ---- layer 2 ----
  if (isE) {
    const unsigned short* w2hS = w2ph + (long)slot * 16384 + l * 8;
    const unsigned short* w2lS = w2pl + (long)slot * 16384 + l * 8;
    int nt2 = w;
    f32x4 acc2[2];
    acc2[0] = (f32x4){0.f, 0.f, 0.f, 0.f};
    acc2[1] = (f32x4){0.f, 0.f, 0.f, 0.f};
#pragma unroll
    for (int ks2 = 0; ks2 < 8; ++ks2) {
      long fo = ((long)nt2 * 8 + ks2) * 512;
      bf16x8 bh = *(const bf16x8*)(w2hS + fo);
      bf16x8 bl = *(const bf16x8*)(w2lS + fo);
#pragma unroll
      for (int mt = 0; mt < 2; ++mt) {
        int row = mt * 16 + lr, kh = ks2 * 32 + lk * 8;
        bf16x8 ah2 = *(const bf16x8*)&Hhi[row][kh];
        bf16x8 al2 = *(const bf16x8*)&Hlo[row][kh];
        acc2[mt] = MFMA16(ah2, bh, acc2[mt], 0, 0, 0);
        acc2[mt] = MFMA16(ah2, bl, acc2[mt], 0, 0, 0);
        acc2[mt] = MFMA16(al2, bh, acc2[mt], 0, 0, 0);
      }
    }
    int col2 = nt2 * 16 + lr;
    float bb2 = b2[col2];
#pragma unroll
    for (int mt = 0; mt < 2; ++mt)
#pragma unroll
      for (int reg = 0; reg < 4; ++reg)
        out[(long)(rowbase + mt * 16 + lk * 4 + reg) * E_ + col2] = acc2[mt][reg] + bb2;
  } else {
    const unsigned short* w2hS = w2ph + (long)slot * 16384 + l * 8;
    const unsigned short* w2lS = w2pl + (long)slot * 16384 + l * 8;
    int mt = w >> 1, nt2 = w & 1;
    f32x4 acc2 = (f32x4){0.f, 0.f, 0.f, 0.f};
#pragma unroll
    for (int ks2 = 0; ks2 < 8; ++ks2) {
      long fo = ((long)nt2 * 8 + ks2) * 512;
      bf16x8 bh = *(const bf16x8*)(w2hS + fo);
      bf16x8 bl = *(const bf16x8*)(w2lS + fo);
      int row = mt * 16 + lr, kh = ks2 * 32 + lk * 8;
      bf16x8 ah2 = *(const bf16x8*)&Hhi[row][kh];
      bf16x8 al2 = *(const bf16x8*)&Hlo[row][kh];
      acc2 = MFMA16(ah2, bh, acc2, 0, 0, 0);
      acc2 = MFMA16(ah2, bl, acc2, 0, 0, 0);
      acc2 = MFMA16(al2, bh, acc2, 0, 0, 0);
    }
    int col2 = nt2 * 16 + lr;
    float bb2 = b2[col2];
#pragma unroll
    for (int reg = 0; reg < 4; ++reg)
      out[(long)(rowbase + mt * 16 + lk * 4 + reg) * R_ + col2] = acc2[reg] + bb2;
  }
}

// ---------------------------------------------------------------------------
// K_gram v2 (unchanged)
// ---------------------------------------------------------------------------
__global__ __launch_bounds__(256) void k_gram(
    const float* __restrict__ e1, const float* __restrict__ e2,
    const float* __restrict__ r1, const float* __restrict__ r2,
    const float* __restrict__ r3, float* __restrict__ Wt) {
  int b = blockIdx.x / 9, m = blockIdx.x % 9;
  const float* sE = ((m < 6) ? e1 : e2) + (long)b * S_ * E_;
  const float* jE = ((m == 2 || m == 5 || m == 8) ? e2 : e1) + (long)b * S_ * E_;
  int sk = m / 3, jk = m % 3;
  const float* sR = ((sk == 0) ? r1 : (sk == 1) ? r2 : r3) + (long)b * S_ * R_;
  const float* jR = ((jk == 0) ? r1 : (jk == 1) ? r2 : r3) + (long)b * S_ * R_;

  __shared__ float Es[64][68], Ej[64][68], Rs[64][36], Rj[64][36];
  int tid = threadIdx.x;
  for (int i = tid; i < 1024; i += 256) {
    int row = i >> 4, c = i & 15;
    *(float4*)&Es[row][4 * c] = *(const float4*)(sE + row * 64 + 4 * c);
    *(float4*)&Ej[row][4 * c] = *(const float4*)(jE + row * 64 + 4 * c);
  }
  for (int i = tid; i < 512; i += 256) {
    int row = i >> 3, c = i & 7;
    *(float4*)&Rs[row][4 * c] = *(const float4*)(sR + row * 32 + 4 * c);
    *(float4*)&Rj[row][4 * c] = *(const float4*)(jR + row * 32 + 4 * c);
  }
  __syncthreads();

  int s0 = (tid & 15) * 4, j0 = (tid >> 4) * 4;
  float ed[4][4] = {}, rd[4][4] = {};
#pragma unroll 4
  for (int k = 0; k < 16; ++k) {
    float4 es[4], ej[4];
#pragma unroll
    for (int i = 0; i < 4; ++i) {
      es[i] = *(const float4*)&Es[s0 + i][4 * k];
      ej[i] = *(const float4*)&Ej[j0 + i][4 * k];
    }
#pragma unroll
    for (int i = 0; i < 4; ++i)
#pragma unroll
      for (int j = 0; j < 4; ++j)
        ed[i][j] = fmaf(es[i].x, ej[j].x, fmaf(es[i].y, ej[j].y,
                   fmaf(es[i].z, ej[j].z, fmaf(es[i].w, ej[j].w, ed[i][j]))));
  }
#pragma unroll 4
  for (int k = 0; k < 8; ++k) {
    float4 rs[4], rj[4];
#pragma unroll
    for (int i = 0; i < 4; ++i) {
      rs[i] = *(const float4*)&Rs[s0 + i][4 * k];
      rj[i] = *(const float4*)&Rj[j0 + i][4 * k];
    }
#pragma unroll
    for (int i = 0; i < 4; ++i)
#pragma unroll
      for (int j = 0; j < 4; ++j)
        rd[i][j] = fmaf(rs[i].x, rj[j].x, fmaf(rs[i].y, rj[j].y,
                   fmaf(rs[i].z, rj[j].z, fmaf(rs[i].w, rj[j].w, rd[i][j]))));
  }
  float* wout = Wt + (long)(b * 9 + m) * 4096;
#pragma unroll
  for (int jj = 0; jj < 4; ++jj) {
    float4 o4 = make_float4(ed[0][jj] * rd[0][jj], ed[1][jj] * rd[1][jj],
                            ed[2][jj] * rd[2][jj], ed[3][jj] * rd[3][jj]);
    *(float4*)(wout + (j0 + jj) * 64 + s0) = o4;
  }
}

// ---------------------------------------------------------------------------
// K_scan v7 (unchanged)
// ---------------------------------------------------------------------------
__global__ __launch_bounds__(256) void k_scan(
    const float* __restrict__ e1g, const float* __restrict__ e2g,
    const float* __restrict__ Wt, float4* __restrict__ acd) {
  __shared__ float WtL[8][64][12];
  int b = blockIdx.x & 63;
  int gq = blockIdx.x >> 6;        // 0..3
  int tid = threadIdx.x;
  int wv = tid >> 6;
  int lane = tid & 63;             // = s
  int fbase = gq * 16 + wv * 4;    // lane handles f = fbase..fbase+3
  const float* Wb = Wt + (long)b * 9 * 4096;
  long eoff = ((long)b * 64 + lane) * 64;
  float4 e1v = *(const float4*)(e1g + eoff + fbase);
  float4 e2v = *(const float4*)(e2g + eoff + fbase);
  float e1a[4] = {e1v.x, e1v.y, e1v.z, e1v.w};
  float e2a[4] = {e2v.x, e2v.y, e2v.z, e2v.w};

  float pW[4], pM[4], pB[4], ca[4], cc[4], cd[4], ka[4], kc[4], kd[4];
#pragma unroll
  for (int f = 0; f < 4; ++f) {
    pW[f] = pM[f] = pB[f] = 0.f;
    ka[f] = kc[f] = kd[f] = 0.f;
    ca[f] = e2a[f]; cc[f] = 0.f; cd[f] = e1a[f];
  }

  for (int jc = 0; jc < 8; ++jc) {
    __syncthreads();
#pragma unroll
    for (int t = 0; t < 2; ++t) {
      int jj = wv * 2 + t;
      const float* src = Wb + jc * 512 + jj * 64 + lane;
      float v[9];
#pragma unroll
      for (int m = 0; m < 9; ++m) v[m] = src[m * 4096];
      float* dst = &WtL[jj][lane][0];
      *(float4*)dst = make_float4(v[0], v[1], v[2], v[3]);
      *(float4*)(dst + 4) = make_float4(v[4], v[5], v[6], v[7]);
      dst[8] = v[8];
    }
    __syncthreads();
#pragma unroll
    for (int jj = 0; jj < 8; ++jj) {
      int j = jc * 8 + jj;
      const float* wrow = &WtL[jj][lane][0];
      float4 w03 = *(const float4*)wrow;
      float4 w47 = *(const float4*)(wrow + 4);
      float bd = wrow[8];
      float wa = w03.x, wc = w03.y, wd = w03.z;
      float ma = w03.w, mc = w47.x, md = w47.y;
      float ba = w47.z, bc = w47.w;
      bool own = (lane == j);
#pragma unroll
      for (int f = 0; f < 4; ++f) {
        float aj = bcastf(ca[f], j);
        float cj = bcastf(cc[f], j);
        float dj = bcastf(cd[f], j);
        ka[f] = own ? ca[f] : ka[f];
        kc[f] = own ? cc[f] : kc[f];
        kd[f] = own ? cd[f] : kd[f];
        pW[f] = fmaf(wa, aj, pW[f]); pW[f] = fmaf(wc, cj, pW[f]); pW[f] = fmaf(wd, dj, pW[f]);
        pM[f] = fmaf(ma, aj, pM[f]); pM[f] = fmaf(mc, cj, pM[f]); pM[f] = fmaf(md, dj, pM[f]);
        pB[f] = fmaf(ba, aj, pB[f]); pB[f] = fmaf(bc, cj, pB[f]); pB[f] = fmaf(bd, dj, pB[f]);
        ca[f] = e2a[f] - pW[f]; cc[f] = pW[f] - pM[f]; cd[f] = e1a[f] - pB[f];
      }
    }
  }
#pragma unroll
  for (int f = 0; f < 4; ++f)
    acd[eoff + fbase + f] = make_float4(ka[f], kc[f], kd[f], 0.f);
}

// ---------------------------------------------------------------------------
// K_infer: reverted to the proven 1024-thread version (R5).  64 blocks only,
// so wide TLP is its latency hiding: 16 waves stage acd, 8 thr/dot u-phase,
// 16 thr/f part-phase.
// ---------------------------------------------------------------------------
__global__ __launch_bounds__(1024) void k_infer(
    const float4* __restrict__ acd,
    const float* __restrict__ e1, const float* __restrict__ e2,
    const float* __restrict__ r1, const float* __restrict__ r2,
    const float* __restrict__ r3,
    const float* __restrict__ qe1, const float* __restrict__ qr1,
    const float* __restrict__ qr2, const float* __restrict__ qr3,
    const float* __restrict__ lng, const float* __restrict__ lnb,
    float* __restrict__ isum) {
  int b = blockIdx.x, tid = threadIdx.x;
  __shared__ float hista[64 * 65], histc[64 * 65], histd[64 * 65];
  __shared__ float vlds[9 * 64];
  __shared__ float ivec[64];
  __shared__ float u1s[64], u2s[64];
  __shared__ float dsc[64];

  {
    const float4* ab = acd + (long)b * 4096;
    for (int idx = tid; idx < 4096; idx += 1024) {
      float4 hv = ab[idx];
      int j = idx >> 6, f = idx & 63;
      hista[j * 65 + f] = hv.x;
      histc[j * 65 + f] = hv.y;
      histd[j * 65 + f] = hv.z;
    }
  }
  if (tid < 576) {
    int pk = tid >> 6, j = tid & 63;
    int p = pk / 3, k = pk % 3;
    const float* rv = ((k == 0) ? r1 : (k == 1) ? r2 : r3) + ((long)b * 64 + j) * 32;
    const float* q = ((p == 0) ? qr1 : (p == 1) ? qr2 : qr3) + b * 32;
    float acc = 0.f;
#pragma unroll
    for (int t = 0; t < 8; ++t) {
      float4 rv4 = *(const float4*)(rv + 4 * t);
      float4 q4 = *(const float4*)(q + 4 * t);
      acc = fmaf(rv4.x, q4.x, fmaf(rv4.y, q4.y,
            fmaf(rv4.z, q4.z, fmaf(rv4.w, q4.w, acc))));
    }
    vlds[pk * 64 + j] = acc;
  }
  if (tid < 64) ivec[tid] = qe1[b * 64 + tid];
  __syncthreads();

  int f = tid >> 4, jsl = tid & 15;
  int dotd = tid >> 3, dt = tid & 7;
  int which = dotd >> 6, dj = dotd & 63;
  const float* erow = (which ? e2 : e1) + ((long)b * 64 + dj) * 64 + dt * 8;
  float isacc = 0.f;
  for (int p = 0; p < 3; ++p) {
    {
      float acc = 0.f;
#pragma unroll
      for (int t = 0; t < 8; ++t)
        acc = fmaf(erow[t], ivec[dt * 8 + t], acc);
      acc += __shfl_xor(acc, 1, 64);
      acc += __shfl_xor(acc, 2, 64);
      acc += __shfl_xor(acc, 4, 64);
      if (dt == 0) { if (which) u2s[dj] = acc; else u1s[dj] = acc; }
    }
    __syncthreads();
    float part = 0.f;
#pragma unroll
    for (int i = 0; i < 4; ++i) {
      int j = jsl * 4 + i;
      float ca = u1s[j] * vlds[(p * 3 + 0) * 64 + j];
      float cc = u1s[j] * vlds[(p * 3 + 1) * 64 + j];
      float cd = u2s[j] * vlds[(p * 3 + 2) * 64 + j];
      part = fmaf(ca, hista[j * 65 + f],
             fmaf(cc, histc[j * 65 + f],
             fmaf(cd, histd[j * 65 + f], part)));
    }
    part += __shfl_xor(part, 1, 64);
    part += __shfl_xor(part, 2, 64);
    part += __shfl_xor(part, 4, 64);
    part += __shfl_xor(part, 8, 64);
    if (jsl == 0) dsc[f] = part;
    __syncthreads();
    if (tid < 64) {
      float v = dsc[tid];
      float mu = v;
#pragma unroll
      for (int mm = 1; mm <= 32; mm <<= 1) mu += __shfl_xor(mu, mm, 64);
      mu *= (1.f / 64.f);
      float d = v - mu;
      float vr = d * d;
#pragma unroll
      for (int mm = 1; mm <= 32; mm <<= 1) vr += __shfl_xor(vr, mm, 64);
      vr *= (1.f / 64.f);
      float iv = d * (1.f / sqrtf(vr + 1e-5f)) * lng[p * 64 + tid] + lnb[p * 64 + tid];
      ivec[tid] = iv;
      isacc += iv;
    }
    __syncthreads();
  }
  if (tid < 64) isum[b * 64 + tid] = isacc;
}

// ---------------------------------------------------------------------------
// K5 (unchanged)
// ---------------------------------------------------------------------------
__global__ __launch_bounds__(256) void k_final(
    const float* __restrict__ isum, const float* __restrict__ Zm,
    float* __restrict__ out) {
  __shared__ float isT[64 * 68];
  int tid = threadIdx.x;
  for (int i = tid; i < 4096; i += 256) {
    int bb = i >> 6, e = i & 63;
    isT[e * 68 + bb] = isum[i];
  }
  __syncthreads();
  int tr = tid >> 4, tc = tid & 15;
  int v0 = blockIdx.x * 64 + tc * 4;
  float acc[4][4] = {};
#pragma unroll 2
  for (int e = 0; e < 64; ++e) {
    float4 a4 = *(const float4*)&isT[e * 68 + 4 * tr];
    float4 z4 = *(const float4*)(Zm + (long)e * V_ + v0);
    float as[4] = {a4.x, a4.y, a4.z, a4.w};
    float zs[4] = {z4.x, z4.y, z4.z, z4.w};
#pragma unroll
    for (int i = 0; i < 4; ++i)
#pragma unroll
      for (int j = 0; j < 4; ++j) acc[i][j] = fmaf(as[i], zs[j], acc[i][j]);
  }
#pragma unroll
  for (int i = 0; i < 4; ++i) {
    float4 o4 = make_float4(acc[i][0], acc[i][1], acc[i][2], acc[i][3]);
    *(float4*)(out + (long)(4 * tr + i) * V_ + v0) = o4;
  }
}

// ---------------------------------------------------------------------------
extern "C" void kernel_launch(void* const* d_in, const int* in_sizes, int n_in,
                              void* d_out, int out_size, void* d_ws, size_t ws_size,
                              hipStream_t stream) {
  const int* story = (const int*)d_in[0];
  const int* query = (const int*)d_in[1];
  const float* we = (const float*)d_in[2];
  const float* pe = (const float*)d_in[3];
  const float* ueW1 = (const float*)d_in[4];
  const float* ueb1 = (const float*)d_in[5];
  const float* ueW2 = (const float*)d_in[6];
  const float* ueb2 = (const float*)d_in[7];
  const float* urW1 = (const float*)d_in[8];
  const float* urb1 = (const float*)d_in[9];
  const float* urW2 = (const float*)d_in[10];
  const float* urb2 = (const float*)d_in[11];
  const float* ieW1 = (const float*)d_in[12];
  const float* ieb1 = (const float*)d_in[13];
  const float* ieW2 = (const float*)d_in[14];
  const float* ieb2 = (const float*)d_in[15];
  const float* irW1 = (const float*)d_in[16];
  const float* irb1 = (const float*)d_in[17];
  const float* irW2 = (const float*)d_in[18];
  const float* irb2 = (const float*)d_in[19];
  const float* lng = (const float*)d_in[20];
  const float* lnb = (const float*)d_in[21];
  const float* Zm = (const float*)d_in[22];

  float* ws = (float*)d_ws;
  // X region holds bf16 hi/lo in fragment order (4160*128 u16 each)
  unsigned short* Xh = (unsigned short*)ws;
  unsigned short* Xl = Xh + 532480;     // together = old X slot
  float* e1 = ws + 532480;              // 4160*64  = 266240
  float* e2 = e1 + 266240;              // 266240
  float* r1 = e2 + 266240;              // 4160*32  = 133120
  float* r2 = r1 + 133120;              // 133120
  float* r3 = r2 + 133120;              // 133120
  float* isum = r3 + 133120;            // 4096
  float* Wt = isum + 4096;              // 9*64*4096 = 2359296
  float4* acd = (float4*)(Wt + 2359296);  // 64*64*64 float4 = 4 MB
  float* qe1 = e1 + 4096 * 64;
  float* qr1 = r1 + 4096 * 32;
  float* qr2 = r2 + 4096 * 32;
  float* qr3 = r3 + 4096 * 32;
  float* outF = (float*)d_out;

  // Prepped weights alias the Wt region (dead until k_gram runs).
  unsigned short* w1ph = (unsigned short*)Wt;
  unsigned short* w1pl = w1ph + 327680;   // 10*32768
  unsigned short* w2ph = w1pl + 327680;
  unsigned short* w2pl = w2ph + 163840;   // 10*16384

  k_prep<<<4160 + 960, 128, 0, stream>>>(story, query, we, pe, Xh, Xl,
                                         ueW1, urW1, ieW1, irW1,
                                         ueW2, urW2, ieW2, irW2,
                                         w1ph, w1pl, w2ph, w2pl);
  k_mlp<<<130 * 5, 256, 0, stream>>>(Xh, Xl, w1ph, w1pl, w2ph, w2pl,
                                     ueb1, urb1, ieb1, irb1,
                                     ueb2, urb2, ieb2, irb2,
                                     e1, e2, r1, r2, r3);
  k_gram<<<64 * 9, 256, 0, stream>>>(e1, e2, r1, r2, r3, Wt);
  k_scan<<<256, 256, 0, stream>>>(e1, e2, Wt, acd);
  k_infer<<<B_, 1024, 0, stream>>>(acd, e1, e2, r1, r2, r3, qe1, qr1, qr2, qr3,
                                   lng, lnb, isum);
  k_final<<<V_ / 64, 256, 0, stream>>>(isum, Zm, outF);
}